// Round 10
// baseline (412.075 us; speedup 1.0000x reference)
//
#include <hip/hip_runtime.h>

typedef __attribute__((ext_vector_type(8))) short short8;
typedef __attribute__((ext_vector_type(4))) float f32x4;

#define NPTS 131072
#define NOFF 125
#define KERN_USH (NOFF * 16384)   // 2,048,000 bf16 elements

__device__ int g_isf32[4];                                   // per-input f32 flag
__device__ __align__(16) unsigned short g_x[NPTS * 128 + 128]; // x as bf16 (f32 case) + slack
__device__ __align__(16) unsigned short g_kern[KERN_USH + 128]; // packed kern

__device__ __forceinline__ float bf2f(unsigned short u) {
  unsigned int v = ((unsigned int)u) << 16;
  return __builtin_bit_cast(float, v);
}
__device__ __forceinline__ unsigned short f2bf(float f) {
  unsigned int x = __builtin_bit_cast(unsigned int, f);
  x += 0x7fffu + ((x >> 16) & 1u);
  return (unsigned short)(x >> 16);
}
__device__ __forceinline__ float rdf(const void* p, int i, int isf32) {
  return isf32 ? ((const float*)p)[i] : bf2f(((const unsigned short*)p)[i]);
}

// direct global->LDS, 16B per lane; LDS dest = wave-uniform base + lane*16
#define GLD16(gp, lp)                                                        \
  __builtin_amdgcn_global_load_lds(                                          \
      (const __attribute__((address_space(1))) unsigned int*)(gp),           \
      (__attribute__((address_space(3))) unsigned int*)(lp), 16, 0, 0)

// --------------------------------------------------------------------------
// Dtype detection (even-indexed ushorts of true bf16 N(0,1) are ~100% in
// [1e-8, 64]; f32-as-bf16 mantissa halves are ~13%).
// --------------------------------------------------------------------------
__global__ __launch_bounds__(64) void k_detect(const unsigned short* x,
                                               const unsigned short* w,
                                               const unsigned short* s,
                                               const unsigned short* v) {
  const unsigned short* ptrs[4] = {x, w, s, v};
  const int l = threadIdx.x;
  #pragma unroll
  for (int i = 0; i < 4; ++i) {
    const unsigned short u = ptrs[i][2 * l];
    const float a = fabsf(bf2f(u));
    const int good = (u == 0) || (a >= 1e-8f && a <= 64.0f);
    const unsigned long long m = __ballot(good);
    if (l == 0) g_isf32[i] = (__popcll(m) < 45) ? 1 : 0;
  }
}

// Convert x f32 -> bf16 into g_x (no-op when input is already bf16).
__global__ __launch_bounds__(256) void k_convx(const void* xin) {
  if (!g_isf32[0]) return;
  const float* xf = (const float*)xin;
  const int t = blockIdx.x * 256 + threadIdx.x;
  short8 o;
  #pragma unroll
  for (int j = 0; j < 8; ++j) o[j] = (short)f2bf(xf[t * 8 + j]);
  *(short8*)(&g_x[t * 8]) = o;
}

// --------------------------------------------------------------------------
// Kernel-tensor generation: (125,128,128) bf16, fragment-packed for MFMA-B.
// packed[koff*16384 + ((kb*8+nt)*64 + l)*8 + t] =
//   kern[koff][ i = kb*32 + (l>>4)*8 + t ][ j = nt*16 + (l&15) ]
// Self-connection folded into koff==62 (offset (0,0,0)).
// --------------------------------------------------------------------------
__global__ __launch_bounds__(256) void gen_kern(const void* __restrict__ weight,
                                                const void* __restrict__ wscs,
                                                const void* __restrict__ wscv) {
  __shared__ float W[4][32][32];
  __shared__ float embs[5];
  const int wf = g_isf32[1], sf = g_isf32[2], vf = g_isf32[3];
  const int koff = blockIdx.x;
  const int tid = threadIdx.x;
  const int xi = koff % 5, yi = (koff / 5) % 5, zi = koff / 25;
  const float lx = (float)(xi - 2), ly = (float)(yi - 2), lz = (float)(zi - 2);
  const float nrm = sqrtf(lx*lx + ly*ly + lz*lz);
  if (tid < 5) {
    const float step = 2.5f / 6.0f;
    const float vb = step * (float)(tid + 1);
    const float d = (nrm - vb) / step;
    float e = 0.0f;
    if (fabsf(d) < 1.0f) {
      float ds = fminf(fmaxf(d, -1.0f + 1e-6f), 1.0f - 1e-6f);
      e = 1.14136f * expf(2.0f - 1.0f/(1.0f + ds) - 1.0f/(1.0f - ds));
    }
    embs[tid] = e;
  }
  __syncthreads();
  float* Wf = &W[0][0][0];
  for (int m = tid; m < 4096; m += 256) {
    float s = 0.0f;
    #pragma unroll
    for (int b = 0; b < 5; ++b) s += embs[b] * rdf(weight, b*4096 + m, wf);
    Wf[m] = s * (1.0f / 125.0f);
  }
  __syncthreads();
  const float invn = (nrm > 0.0f) ? 1.0f / nrm : 0.0f;
  const float s3 = 1.7320508075688772f;
  const float Y1v0 = s3 * ly * invn;
  const float Y1v1 = s3 * lz * invn;
  const float Y1v2 = s3 * lx * invn;
  const float c  = 0.125f;
  const float cs = 0.125f / s3;
  const bool center = (koff == 62);
  const float inv = 0.17677669529663687f;  // 1/sqrt(32)
  for (int p = tid; p < 16384; p += 256) {
    const int t = p & 7;
    const int l = (p >> 3) & 63;
    const int f = p >> 9;
    const int kb = f >> 3, nt = f & 7;
    const int i = kb*32 + (l >> 4)*8 + t;
    const int j = nt*16 + (l & 15);
    float val;
    if (i < 32) {
      if (j < 32) {
        val = c * W[0][i][j];
        if (center) val += inv * rdf(wscs, i*32 + j, sf);
      } else {
        const int wq = (j - 32) / 3, kk = (j - 32) % 3;
        const float yv = (kk == 0) ? Y1v0 : ((kk == 1) ? Y1v1 : Y1v2);
        val = c * W[1][i][wq] * yv;
      }
    } else {
      const int u = (i - 32) / 3, ii = (i - 32) % 3;
      const float yvi = (ii == 0) ? Y1v0 : ((ii == 1) ? Y1v1 : Y1v2);
      if (j < 32) {
        val = cs * W[3][u][j] * yvi;
      } else {
        const int wq = (j - 32) / 3, kk = (j - 32) % 3;
        val = (ii == kk) ? c * W[2][u][wq] : 0.0f;
        if (center && ii == kk) val += inv * rdf(wscv, u*32 + wq, vf);
      }
    }
    g_kern[koff * 16384 + p] = f2bf(val);
  }
}

// --------------------------------------------------------------------------
// Main conv: 512 WGs x 512 thr (8 waves), 2 blocks/CU, 16 waves/CU.
// Wave = 64 dsts x 64 cols (4 dst-groups x 2 col-halves): halves per-CU
// LDS B-read traffic (the R9 limiter, 6144 cy/ko -> 3072). Gathers are
// exec-masked per lane (valid lanes only -> no TA/L1 tag storm, the R8
// failure). nidx loads + output stores non-temporal. Per-fragment
// act-gating on MFMAs. B: GLD16 double-buffer, one barrier/ko; next-ko
// A gathers issued pre-barrier (drain with the B stage).
// --------------------------------------------------------------------------
__global__ __launch_bounds__(512, 4) void conv_main(
    const unsigned short* __restrict__ xfeat,
    const int* __restrict__ nidx,
    void* __restrict__ out)
{
  __shared__ __align__(16) unsigned short Blds[2][16384];  // 2 x 32 KB
  const int of32 = g_isf32[0];
  const unsigned short* xs = of32 ? g_x : xfeat;
  const int tid = threadIdx.x;
  const int wv = tid >> 6;        // 0..7
  const int l  = tid & 63;
  const int lr = l & 15;
  const int lk = l >> 4;
  const int dg = wv >> 1;         // dst-group 0..3
  const int ch = wv & 1;          // col-half 0..1
  const int m0 = blockIdx.x * 256 + dg * 64;   // wave's 64 dsts

  f32x4 acc[4][4];
  #pragma unroll
  for (int i = 0; i < 4; ++i)
    #pragma unroll
    for (int j = 0; j < 4; ++j) acc[i][j] = (f32x4)0.0f;

  {  // prologue: stage B(0) reg-staged (once)
    const unsigned short* s = g_kern + tid*8;
    short8 p[4];
    #pragma unroll
    for (int c = 0; c < 4; ++c) p[c] = *(const short8*)(s + c*4096);
    #pragma unroll
    for (int c = 0; c < 4; ++c) *(short8*)(&Blds[0][tid*8 + c*4096]) = p[c];
  }

  // prologue: ko=0 validity + masked kb0/kb1 gathers
  bool vl[4], act[4];
  unsigned uoff[4];
  {
    const int* ip = nidx + m0;
    #pragma unroll
    for (int mt = 0; mt < 4; ++mt) {
      const int idx = __builtin_nontemporal_load(ip + mt*16 + lr);
      vl[mt]  = (unsigned)idx < (unsigned)NPTS;
      act[mt] = __any(vl[mt]);
      uoff[mt] = (unsigned)idx * 256u + (unsigned)lk * 16u;
    }
  }
  short8 a[2][4];
  #pragma unroll
  for (int mt = 0; mt < 4; ++mt) {
    a[0][mt] = (short8)(short)0;
    a[1][mt] = (short8)(short)0;
    if (vl[mt]) {
      a[0][mt] = *(const short8*)((const char*)xs + uoff[mt]);
      a[1][mt] = *(const short8*)((const char*)xs + uoff[mt] + 64);
    }
  }
  __syncthreads();

  int cur = 0;
  for (int ko = 0; ko < NOFF; ++ko) {
    const bool hn = (ko + 1 < NOFF);

    // B(ko+1) direct to LDS[cur^1]; drains at end-of-iter barrier
    if (hn) {
      const unsigned short* s = g_kern + (ko + 1) * 16384 + wv*512 + l*8;
      unsigned short* d = &Blds[cur ^ 1][wv*512];
      #pragma unroll
      for (int c = 0; c < 4; ++c) GLD16(s + c*4096, d + c*4096);
    }
    // next-ko indices (non-temporal: streamed once, keep x in L2)
    int idxn[4];
    if (hn) {
      const int* ip = nidx + (size_t)(ko + 1) * NPTS + m0;
      #pragma unroll
      for (int mt = 0; mt < 4; ++mt)
        idxn[mt] = __builtin_nontemporal_load(ip + mt*16 + lr);
    }

    if (act[0] || act[1] || act[2] || act[3]) {
      #pragma unroll
      for (int kb = 0; kb < 4; ++kb) {
        short8 b[4];
        #pragma unroll
        for (int nt = 0; nt < 4; ++nt)
          b[nt] = *(const short8*)(&Blds[cur][((kb*8 + ch*4 + nt)*64 + l)*8]);
        #pragma unroll
        for (int mt = 0; mt < 4; ++mt) {
          if (act[mt]) {
            #pragma unroll
            for (int nt = 0; nt < 4; ++nt)
              acc[mt][nt] = __builtin_amdgcn_mfma_f32_16x16x32_bf16(
                  a[kb & 1][mt], b[nt], acc[mt][nt], 0, 0, 0);
          }
        }
        // refill the just-consumed slot with kb+2 (masked per lane)
        if (kb < 2) {
          #pragma unroll
          for (int mt = 0; mt < 4; ++mt) {
            if (act[mt]) {
              short8 v = (short8)(short)0;
              if (vl[mt])
                v = *(const short8*)((const char*)xs + uoff[mt] + (kb + 2)*64);
              a[kb & 1][mt] = v;
            }
          }
        }
      }
    }

    // next-ko validity + masked kb0/kb1 gathers (drain with the barrier)
    if (hn) {
      #pragma unroll
      for (int mt = 0; mt < 4; ++mt) {
        vl[mt]  = (unsigned)idxn[mt] < (unsigned)NPTS;
        act[mt] = __any(vl[mt]);
        uoff[mt] = (unsigned)idxn[mt] * 256u + (unsigned)lk * 16u;
        short8 v0 = (short8)(short)0, v1 = (short8)(short)0;
        if (vl[mt]) {
          v0 = *(const short8*)((const char*)xs + uoff[mt]);
          v1 = *(const short8*)((const char*)xs + uoff[mt] + 64);
        }
        a[0][mt] = v0;
        a[1][mt] = v1;
      }
    }
    __syncthreads();
    cur ^= 1;
  }

  // epilogue: local row = dg*64 + mt*16 + lk*4 + r, col = ch*64 + nt*16 + lr
  if (of32) {
    float* of = (float*)out;
    #pragma unroll
    for (int mt = 0; mt < 4; ++mt)
      #pragma unroll
      for (int nt = 0; nt < 4; ++nt)
        #pragma unroll
        for (int r = 0; r < 4; ++r)
          __builtin_nontemporal_store(
              acc[mt][nt][r],
              &of[(size_t)(m0 + mt*16 + lk*4 + r) * 128 + ch*64 + nt*16 + lr]);
  } else {
    // block-wide LDS bounce (XOR-swizzled), then coalesced non-temporal stores
    unsigned short* eb = &Blds[0][0];   // 64 KB = 256 rows x 128 cols
    #pragma unroll
    for (int mt = 0; mt < 4; ++mt)
      #pragma unroll
      for (int nt = 0; nt < 4; ++nt)
        #pragma unroll
        for (int r = 0; r < 4; ++r) {
          const int row = dg*64 + mt*16 + lk*4 + r;    // 0..255 local
          const int ush = ch*64 + nt*16 + lr;          // 0..127 in-row
          eb[row*128 + (ush ^ ((row & 7) << 3))] = f2bf(acc[mt][nt][r]);
        }
    __syncthreads();
    unsigned short* ob = (unsigned short*)out;
    const int row = tid >> 1;
    #pragma unroll
    for (int it = 0; it < 8; ++it) {
      const int ub = (tid & 1)*64 + it*8;
      const short8 v = *(const short8*)(&eb[row*128 + (ub ^ ((row & 7) << 3))]);
      __builtin_nontemporal_store(
          v, (short8*)&ob[(size_t)(blockIdx.x*256 + row) * 128 + ub]);
    }
  }
}

extern "C" void kernel_launch(void* const* d_in, const int* in_sizes, int n_in,
                              void* d_out, int out_size, void* d_ws, size_t ws_size,
                              hipStream_t stream) {
  const unsigned short* xfeat  = (const unsigned short*)d_in[0];
  const void*           weight = d_in[1];
  const void*           wscs   = d_in[2];
  const void*           wscv   = d_in[3];
  const int*            nidx   = (const int*)d_in[4];

  hipLaunchKernelGGL(k_detect, dim3(1), dim3(64), 0, stream,
                     (const unsigned short*)d_in[0], (const unsigned short*)d_in[1],
                     (const unsigned short*)d_in[2], (const unsigned short*)d_in[3]);
  hipLaunchKernelGGL(k_convx, dim3(NPTS * 128 / (256 * 8)), dim3(256), 0, stream, d_in[0]);
  hipLaunchKernelGGL(gen_kern, dim3(NOFF), dim3(256), 0, stream, weight, wscs, wscv);
  hipLaunchKernelGGL(conv_main, dim3(NPTS / 256), dim3(512), 0, stream,
                     xfeat, nidx, d_out);
}

// Round 11
// 252.986 us; speedup vs baseline: 1.6288x; 1.6288x over previous
//
#include <hip/hip_runtime.h>

typedef __attribute__((ext_vector_type(8))) short short8;
typedef __attribute__((ext_vector_type(4))) float f32x4;

#define NPTS 131072
#define NOFF 125
#define KERN_USH (NOFF * 8192)   // block-sparse packed kern: 16 KB/offset

__device__ int g_isf32[4];                                     // per-input f32 flag
__device__ __align__(16) unsigned short g_x[NPTS * 128 + 128]; // x, planar layout, bf16
__device__ __align__(16) unsigned short g_kern[KERN_USH + 128];

__device__ __forceinline__ float bf2f(unsigned short u) {
  unsigned int v = ((unsigned int)u) << 16;
  return __builtin_bit_cast(float, v);
}
__device__ __forceinline__ unsigned short f2bf(float f) {
  unsigned int x = __builtin_bit_cast(unsigned int, f);
  x += 0x7fffu + ((x >> 16) & 1u);
  return (unsigned short)(x >> 16);
}
__device__ __forceinline__ float rdf(const void* p, int i, int isf32) {
  return isf32 ? ((const float*)p)[i] : bf2f(((const unsigned short*)p)[i]);
}

// direct global->LDS, 16B per lane; LDS dest = wave-uniform base + lane*16
#define GLD16(gp, lp)                                                        \
  __builtin_amdgcn_global_load_lds(                                          \
      (const __attribute__((address_space(1))) unsigned int*)(gp),           \
      (__attribute__((address_space(3))) unsigned int*)(lp), 16, 0, 0)

// --------------------------------------------------------------------------
// Dtype detection (even-indexed ushorts of true bf16 N(0,1) are ~100% in
// [1e-8, 64]; f32-as-bf16 mantissa halves are ~13%).
// --------------------------------------------------------------------------
__global__ __launch_bounds__(64) void k_detect(const unsigned short* x,
                                               const unsigned short* w,
                                               const unsigned short* s,
                                               const unsigned short* v) {
  const unsigned short* ptrs[4] = {x, w, s, v};
  const int l = threadIdx.x;
  #pragma unroll
  for (int i = 0; i < 4; ++i) {
    const unsigned short u = ptrs[i][2 * l];
    const float a = fabsf(bf2f(u));
    const int good = (u == 0) || (a >= 1e-8f && a <= 64.0f);
    const unsigned long long m = __ballot(good);
    if (l == 0) g_isf32[i] = (__popcll(m) < 45) ? 1 : 0;
  }
}

// Materialize g_x in PLANAR layout: col cp<32 -> x[cp];
// cp = 32 + i*32 + u  ->  x[32 + u*3 + i].  (both dtypes)
__global__ __launch_bounds__(256) void k_convx(const void* xin) {
  const int t = blockIdx.x * 256 + threadIdx.x;
  const int n = t >> 4;
  const int cp0 = (t & 15) * 8;
  const size_t rb = (size_t)n * 128;
  short8 o;
  if (g_isf32[0]) {
    const float* xf = (const float*)xin;
    #pragma unroll
    for (int j = 0; j < 8; ++j) {
      const int cp = cp0 + j;
      const int src = cp < 32 ? cp : 32 + ((cp - 32) & 31) * 3 + ((cp - 32) >> 5);
      o[j] = (short)f2bf(xf[rb + src]);
    }
  } else {
    const unsigned short* xb = (const unsigned short*)xin;
    #pragma unroll
    for (int j = 0; j < 8; ++j) {
      const int cp = cp0 + j;
      const int src = cp < 32 ? cp : 32 + ((cp - 32) & 31) * 3 + ((cp - 32) >> 5);
      o[j] = (short)xb[rb + src];
    }
  }
  *(short8*)(&g_x[rb + cp0]) = o;
}

// --------------------------------------------------------------------------
// Block-sparse packed kernel, planar basis. 16 blocks of 512 ush per ko
// (only nonzero ones stored): blk 0..7 = col-s region (kb=blk>>1 row-block,
// nt=blk&1): kb==0 -> Kss, kb==1+i -> Kvs_i. blk 8..13 = Ksv_k (k=(blk-8)>>1).
// blk 14..15 = shared vv block c*Wc. Fragment layout within a block:
// ush[(blk*64 + lane)*8 + t] = Block[u=(lane>>4)*8+t][w=(blk&1)*16+(lane&15)].
// Self-connection folded at koff==62.
// --------------------------------------------------------------------------
__global__ __launch_bounds__(256) void gen_kern(const void* __restrict__ weight,
                                                const void* __restrict__ wscs,
                                                const void* __restrict__ wscv) {
  __shared__ float W[4][32][32];
  __shared__ float embs[5];
  const int wf = g_isf32[1], sf = g_isf32[2], vf = g_isf32[3];
  const int koff = blockIdx.x;
  const int tid = threadIdx.x;
  const int xi = koff % 5, yi = (koff / 5) % 5, zi = koff / 25;
  const float lx = (float)(xi - 2), ly = (float)(yi - 2), lz = (float)(zi - 2);
  const float nrm = sqrtf(lx*lx + ly*ly + lz*lz);
  if (tid < 5) {
    const float step = 2.5f / 6.0f;
    const float vb = step * (float)(tid + 1);
    const float d = (nrm - vb) / step;
    float e = 0.0f;
    if (fabsf(d) < 1.0f) {
      float ds = fminf(fmaxf(d, -1.0f + 1e-6f), 1.0f - 1e-6f);
      e = 1.14136f * expf(2.0f - 1.0f/(1.0f + ds) - 1.0f/(1.0f - ds));
    }
    embs[tid] = e;
  }
  __syncthreads();
  float* Wf = &W[0][0][0];
  for (int m = tid; m < 4096; m += 256) {
    float s = 0.0f;
    #pragma unroll
    for (int b = 0; b < 5; ++b) s += embs[b] * rdf(weight, b*4096 + m, wf);
    Wf[m] = s * (1.0f / 125.0f);
  }
  __syncthreads();
  const float invn = (nrm > 0.0f) ? 1.0f / nrm : 0.0f;
  const float s3 = 1.7320508075688772f;
  const float Y1v0 = s3 * ly * invn;
  const float Y1v1 = s3 * lz * invn;
  const float Y1v2 = s3 * lx * invn;
  const float c  = 0.125f;
  const float cs = 0.125f / s3;
  const bool center = (koff == 62);
  const float inv = 0.17677669529663687f;  // 1/sqrt(32)
  for (int p = tid; p < 8192; p += 256) {
    const int t = p & 7;
    const int lane = (p >> 3) & 63;
    const int blk = p >> 9;                      // 0..15
    const int u = ((lane >> 4) << 3) + t;        // 0..31
    const int w = (blk & 1) * 16 + (lane & 15);  // 0..31
    float val;
    if (blk < 8) {
      const int kb = blk >> 1;
      if (kb == 0) {
        val = c * W[0][u][w];
        if (center) val += inv * rdf(wscs, u*32 + w, sf);
      } else {
        const int i = kb - 1;
        const float y = (i == 0) ? Y1v0 : ((i == 1) ? Y1v1 : Y1v2);
        val = cs * W[3][u][w] * y;
      }
    } else if (blk < 14) {
      const int k = (blk - 8) >> 1;
      const float y = (k == 0) ? Y1v0 : ((k == 1) ? Y1v1 : Y1v2);
      val = c * W[1][u][w] * y;
    } else {
      val = c * W[2][u][w];
      if (center) val += inv * rdf(wscv, u*32 + w, vf);
    }
    g_kern[koff * 8192 + p] = f2bf(val);
  }
}

// --------------------------------------------------------------------------
// Main conv: 512 WGs x 512 thr (8 waves), 2 blocks/CU, 16 waves/CU.
// Wave = 32 dsts x 128 cols (R9 geometry). Block-sparse B: 16 LDS b128
// reads/wave/ko (was 32), 40 MFMA/wave/ko (was 64), vv block shared
// across the 3 components. Exec-masked gathers (planar g_x), nt index
// loads/stores, per-fragment act-gating. B: GLD16 double-buffer 2x16KB,
// one barrier/ko; next-ko A gathers issued pre-barrier.
// --------------------------------------------------------------------------
__global__ __launch_bounds__(512, 4) void conv_main(
    const int* __restrict__ nidx,
    void* __restrict__ out)
{
  __shared__ __align__(16) unsigned short Buf[32768];  // 64 KB; B dbuf = first 32 KB
  const int of32 = g_isf32[0];
  const char* xb = (const char*)g_x;
  const int tid = threadIdx.x;
  const int wv = tid >> 6;        // 0..7
  const int l  = tid & 63;
  const int lr = l & 15;
  const int lk = l >> 4;
  const int m0 = blockIdx.x * 256 + wv * 32;   // wave's 32 dsts

  f32x4 acc[2][8];
  #pragma unroll
  for (int i = 0; i < 2; ++i)
    #pragma unroll
    for (int j = 0; j < 8; ++j) acc[i][j] = (f32x4)0.0f;

  {  // prologue: stage B(0) reg-staged (once): 16 KB / 512 thr = 2 x 16B
    const unsigned short* s = g_kern + tid*8;
    short8 p0 = *(const short8*)(s);
    short8 p1 = *(const short8*)(s + 4096);
    *(short8*)(&Buf[tid*8])        = p0;
    *(short8*)(&Buf[tid*8 + 4096]) = p1;
  }

  // prologue: ko=0 validity + all-4-kb masked gathers
  bool vl[2], act[2];
  unsigned uoff[2];
  {
    const int* ip = nidx + m0;
    #pragma unroll
    for (int mt = 0; mt < 2; ++mt) {
      const int idx = __builtin_nontemporal_load(ip + mt*16 + lr);
      vl[mt]  = (unsigned)idx < (unsigned)NPTS;
      act[mt] = __any(vl[mt]);
      uoff[mt] = (unsigned)idx * 256u + (unsigned)lk * 16u;
    }
  }
  short8 a[4][2];
  #pragma unroll
  for (int mt = 0; mt < 2; ++mt) {
    #pragma unroll
    for (int kb = 0; kb < 4; ++kb) {
      short8 v = (short8)(short)0;
      if (vl[mt]) v = *(const short8*)(xb + uoff[mt] + kb*64);
      a[kb][mt] = v;
    }
  }
  __syncthreads();

  int cur = 0;
  for (int ko = 0; ko < NOFF; ++ko) {
    const bool hn = (ko + 1 < NOFF);

    // B(ko+1) direct to LDS[cur^1]; drains at end-of-iter barrier
    if (hn) {
      const unsigned short* s = g_kern + (ko + 1) * 8192 + wv*512 + l*8;
      unsigned short* d = &Buf[(cur ^ 1) * 8192 + wv*512];
      GLD16(s, d);
      GLD16(s + 4096, d + 4096);
    }
    // next-ko indices (non-temporal)
    int idxn[2];
    if (hn) {
      const int* ip = nidx + (size_t)(ko + 1) * NPTS + m0;
      #pragma unroll
      for (int mt = 0; mt < 2; ++mt)
        idxn[mt] = __builtin_nontemporal_load(ip + mt*16 + lr);
    }

    const unsigned short* B = &Buf[cur * 8192];
    if (act[0] || act[1]) {
      // ---- col-s block (planar cols 0..31): dense over 4 row-blocks ----
      #pragma unroll
      for (int kb = 0; kb < 4; ++kb) {
        const short8 bs0 = *(const short8*)(&B[((kb*2 + 0)*64 + l)*8]);
        const short8 bs1 = *(const short8*)(&B[((kb*2 + 1)*64 + l)*8]);
        #pragma unroll
        for (int mt = 0; mt < 2; ++mt) {
          if (act[mt]) {
            acc[mt][0] = __builtin_amdgcn_mfma_f32_16x16x32_bf16(
                a[kb][mt], bs0, acc[mt][0], 0, 0, 0);
            acc[mt][1] = __builtin_amdgcn_mfma_f32_16x16x32_bf16(
                a[kb][mt], bs1, acc[mt][1], 0, 0, 0);
          }
        }
      }
      // ---- v col-blocks: out_vi = xs @ Ksv_i + xv_i @ (c*Wc)  ----
      const short8 bv0 = *(const short8*)(&B[(14*64 + l)*8]);
      const short8 bv1 = *(const short8*)(&B[(15*64 + l)*8]);
      #pragma unroll
      for (int i = 0; i < 3; ++i) {
        const short8 bsv0 = *(const short8*)(&B[((8 + i*2)*64 + l)*8]);
        const short8 bsv1 = *(const short8*)(&B[((9 + i*2)*64 + l)*8]);
        #pragma unroll
        for (int mt = 0; mt < 2; ++mt) {
          if (act[mt]) {
            acc[mt][2 + 2*i] = __builtin_amdgcn_mfma_f32_16x16x32_bf16(
                a[0][mt], bsv0, acc[mt][2 + 2*i], 0, 0, 0);
            acc[mt][2 + 2*i] = __builtin_amdgcn_mfma_f32_16x16x32_bf16(
                a[1 + i][mt], bv0, acc[mt][2 + 2*i], 0, 0, 0);
            acc[mt][3 + 2*i] = __builtin_amdgcn_mfma_f32_16x16x32_bf16(
                a[0][mt], bsv1, acc[mt][3 + 2*i], 0, 0, 0);
            acc[mt][3 + 2*i] = __builtin_amdgcn_mfma_f32_16x16x32_bf16(
                a[1 + i][mt], bv1, acc[mt][3 + 2*i], 0, 0, 0);
          }
        }
      }
    }

    // next-ko validity + all-4-kb masked gathers (drain with the barrier)
    if (hn) {
      #pragma unroll
      for (int mt = 0; mt < 2; ++mt) {
        vl[mt]  = (unsigned)idxn[mt] < (unsigned)NPTS;
        act[mt] = __any(vl[mt]);
        uoff[mt] = (unsigned)idxn[mt] * 256u + (unsigned)lk * 16u;
        #pragma unroll
        for (int kb = 0; kb < 4; ++kb) {
          short8 v = (short8)(short)0;
          if (vl[mt]) v = *(const short8*)(xb + uoff[mt] + kb*64);
          a[kb][mt] = v;
        }
      }
    }
    __syncthreads();
    cur ^= 1;
  }

  // epilogue: planar acc -> ORIGINAL interleaved columns.
  // q<2: oc = q*16+lr. q>=2: i=(q-2)>>1, h=(q-2)&1 -> oc = 32+(h*16+lr)*3+i.
  if (of32) {
    float* of = (float*)out;
    #pragma unroll
    for (int mt = 0; mt < 2; ++mt)
      #pragma unroll
      for (int q = 0; q < 8; ++q) {
        const int oc = (q < 2) ? (q*16 + lr)
                               : 32 + (((q - 2) & 1)*16 + lr)*3 + ((q - 2) >> 1);
        #pragma unroll
        for (int r = 0; r < 4; ++r)
          __builtin_nontemporal_store(
              acc[mt][q][r],
              &of[(size_t)(m0 + mt*16 + lk*4 + r) * 128 + oc]);
      }
  } else {
    // block-wide LDS bounce (XOR-swizzled, un-permutes), coalesced nt stores
    unsigned short* eb = &Buf[0];   // 64 KB = 256 rows x 128 cols
    #pragma unroll
    for (int mt = 0; mt < 2; ++mt)
      #pragma unroll
      for (int q = 0; q < 8; ++q) {
        const int oc = (q < 2) ? (q*16 + lr)
                               : 32 + (((q - 2) & 1)*16 + lr)*3 + ((q - 2) >> 1);
        #pragma unroll
        for (int r = 0; r < 4; ++r) {
          const int row = wv*32 + mt*16 + lk*4 + r;    // 0..255 local
          eb[row*128 + (oc ^ ((row & 7) << 3))] = f2bf(acc[mt][q][r]);
        }
      }
    __syncthreads();
    unsigned short* ob = (unsigned short*)out;
    const int row = tid >> 1;
    #pragma unroll
    for (int it = 0; it < 8; ++it) {
      const int ub = (tid & 1)*64 + it*8;
      const short8 v = *(const short8*)(&eb[row*128 + (ub ^ ((row & 7) << 3))]);
      __builtin_nontemporal_store(
          v, (short8*)&ob[(size_t)(blockIdx.x*256 + row) * 128 + ub]);
    }
  }
}

extern "C" void kernel_launch(void* const* d_in, const int* in_sizes, int n_in,
                              void* d_out, int out_size, void* d_ws, size_t ws_size,
                              hipStream_t stream) {
  const void* weight = d_in[1];
  const void* wscs   = d_in[2];
  const void* wscv   = d_in[3];
  const int*  nidx   = (const int*)d_in[4];

  hipLaunchKernelGGL(k_detect, dim3(1), dim3(64), 0, stream,
                     (const unsigned short*)d_in[0], (const unsigned short*)d_in[1],
                     (const unsigned short*)d_in[2], (const unsigned short*)d_in[3]);
  hipLaunchKernelGGL(k_convx, dim3(NPTS * 128 / (256 * 8)), dim3(256), 0, stream, d_in[0]);
  hipLaunchKernelGGL(gen_kern, dim3(NOFF), dim3(256), 0, stream, weight, wscs, wscv);
  hipLaunchKernelGGL(conv_main, dim3(NPTS / 256), dim3(512), 0, stream,
                     nidx, d_out);
}